// Round 9
// baseline (74.671 us; speedup 1.0000x reference)
//
#include <hip/hip_runtime.h>
#include <cstdint>

// AttentionFlow — fused MFMA; 64-row tiles, 16 waves/block (1024 thr),
// XCD-batch pinning, prefetch-under-staging, q2c fused, flash-merge tail.
// B=8, T=2048, I=512, D=512. Output (B,T,4D) fp32.

constexpr int kB = 8;
constexpr int kT = 2048;
constexpr int kI = 512;
constexpr int kD = 512;
constexpr int kW = 4 * kD;
constexpr int kRows = 64;                // t-rows per block
constexpr int kTiles = kT / kRows;       // 32 tiles per batch
constexpr int kChunk = kRows * 72;       // LDS bytes per k-chunk (4608)

using f32x4  = __attribute__((ext_vector_type(4))) float;
using bf16x4 = __attribute__((ext_vector_type(4))) __bf16;
using bf16x8 = __attribute__((ext_vector_type(8))) __bf16;

__device__ __forceinline__ float dot8(const f32x4& a0, const f32x4& a1,
                                      const f32x4& b0, const f32x4& b1) {
  return a0.x * b0.x + a0.y * b0.y + a0.z * b0.z + a0.w * b0.w +
         a1.x * b1.x + a1.y * b1.y + a1.z * b1.z + a1.w * b1.w;
}

// qf[((b*32+g)*16+kk)*512 + lane*8 + j] = bf16(q[b][g*16+(lane&15)]
//                                               [kk*32+(lane>>4)*8+j]) + sq
__global__ __launch_bounds__(256) void prep_qf_kernel(
    const float* __restrict__ q, const float* __restrict__ w_q,
    const float* __restrict__ b_q, float* __restrict__ sq,
    __bf16* __restrict__ qf) {
  __shared__ float sacc[16][17];
  const int b = blockIdx.y;
  const int g = blockIdx.x;  // 0..31
  const int tid = threadIdx.x;
  const int kk0 = tid >> 6;
  const int lane = tid & 63;
  const int lr = lane & 15, lg = lane >> 4;
  const float* row = q + ((size_t)(b * kI + g * 16 + lr)) * kD;
  float sp = 0.f;
#pragma unroll
  for (int kk = kk0; kk < 16; kk += 4) {
    const int ka = kk * 32 + lg * 8;
    f32x4 v0 = *(const f32x4*)(row + ka);
    f32x4 v1 = *(const f32x4*)(row + ka + 4);
    f32x4 u0 = *(const f32x4*)(w_q + ka);
    f32x4 u1 = *(const f32x4*)(w_q + ka + 4);
    sp += dot8(v0, v1, u0, u1);
    bf16x8 o = {(__bf16)v0.x, (__bf16)v0.y, (__bf16)v0.z, (__bf16)v0.w,
                (__bf16)v1.x, (__bf16)v1.y, (__bf16)v1.z, (__bf16)v1.w};
    *(bf16x8*)(qf + ((((size_t)(b * 32 + g)) * 16 + kk) << 9) + lane * 8) = o;
  }
  sacc[lr][kk0 * 4 + lg] = sp;
  __syncthreads();
  if (tid < 16) {
    float s = 0.f;
#pragma unroll
    for (int j = 0; j < 16; ++j) s += sacc[tid][j];
    sq[b * kI + g * 16 + tid] = s + b_q[0];
  }
}

// vf[((b*32+gd)*16+kki)*512 + lane*8 + j] = bf16(q[b][kki*32+(lane>>4)*8+j]
//                                                 [gd*16+(lane&15)])
__global__ __launch_bounds__(256) void prep_vf_kernel(
    const float* __restrict__ q, __bf16* __restrict__ vf) {
  __shared__ float ts[64][68];
  const int b = blockIdx.z;
  const int i0 = blockIdx.x * 64;
  const int d0 = blockIdx.y * 64;
  const int tid = threadIdx.x;
  const int r = tid >> 2;
  const int cg = (tid & 3) * 16;
#pragma unroll
  for (int j = 0; j < 4; ++j) {
    f32x4 v = *(const f32x4*)(q + ((size_t)(b * kI + i0 + r)) * kD + d0 + cg + 4 * j);
    ts[r][cg + 4 * j + 0] = v.x;
    ts[r][cg + 4 * j + 1] = v.y;
    ts[r][cg + 4 * j + 2] = v.z;
    ts[r][cg + 4 * j + 3] = v.w;
  }
  __syncthreads();
  const int dl = tid >> 2;
  const int ig = (tid & 3) * 16;
  bf16x8 o0, o1;
#pragma unroll
  for (int j = 0; j < 8; ++j) o0[j] = (__bf16)ts[ig + j][dl];
#pragma unroll
  for (int j = 0; j < 8; ++j) o1[j] = (__bf16)ts[ig + 8 + j][dl];
  const int gd = (d0 >> 4) + (dl >> 4);
  const int lr = dl & 15;
  const int kki0 = (i0 >> 5) + (ig >> 5);
  const int lg0 = (ig & 31) >> 3;
  const int i1 = ig + 8;
  const int kki1 = (i0 >> 5) + (i1 >> 5);
  const int lg1 = (i1 & 31) >> 3;
  *(bf16x8*)(vf + ((((size_t)(b * 32 + gd)) * 16 + kki0) << 9) +
             (lg0 * 16 + lr) * 8) = o0;
  *(bf16x8*)(vf + ((((size_t)(b * 32 + gd)) * 16 + kki1) << 9) +
             (lg1 * 16 + lr) * 8) = o1;
}

__global__ __launch_bounds__(1024, 4) void fused_attn(
    const float* __restrict__ c, const __bf16* __restrict__ qf,
    const __bf16* __restrict__ vf, const float* __restrict__ w_cq,
    const float* __restrict__ w_c, const float* __restrict__ b_c,
    const float* __restrict__ b_cq, const float* __restrict__ sq,
    float* __restrict__ out, float* __restrict__ mz,
    float* __restrict__ u_tile) {
  // lAP: 16 k-chunks x 64 rows x 72B (A in phase 1, P in phase 2) = 73728 B
  __shared__ __align__(16) char lAP[16 * kChunk];
  __shared__ float scrow[kRows];
  __shared__ float redm[16 * kRows];
  __shared__ float rfin[kRows];
  __shared__ float sfin[kRows];

  const int bid = blockIdx.x;
  const int b = bid & 7;        // batch == XCD slot (256 % 8 == 0)
  const int tile = bid >> 3;    // 0..31
  const int t0 = tile * kRows;
  const int tid = threadIdx.x;
  const int w = tid >> 6;       // 0..15: 32-wide i (phase1) / d (phase2) slice
  const int lane = tid & 63;
  const int lr = lane & 15, lg = lane >> 4;

  // ---- issue phase-1 B prefetch BEFORE staging (flies under c reads) ----
  const __bf16* qg0 = qf + (((size_t)(b * 32 + 2 * w + 0)) * 16 << 9) + lane * 8;
  const __bf16* qg1 = qf + (((size_t)(b * 32 + 2 * w + 1)) * 16 << 9) + lane * 8;
  bf16x8 b0[2], b1[2], b2[2];
  b0[0] = *(const bf16x8*)(qg0);
  b0[1] = *(const bf16x8*)(qg1);
  b1[0] = *(const bf16x8*)(qg0 + (1 << 9));
  b1[1] = *(const bf16x8*)(qg1 + (1 << 9));

  // ---- stage A = bf16(c .* w_cq) -> lAP; slot0=c; sc rowdot folded ------
  {
    const int srow = tid >> 4;       // 0..63
    const int col4 = (tid & 15) * 4; // 0..60
    const float* crow = c + ((size_t)(b * kT + t0 + srow)) * kD;
    float* orow0 = out + ((size_t)(b * kT + t0 + srow)) * kW;
    float scp = 0.f;
#pragma unroll
    for (int j = 0; j < 8; ++j) {
      const int col = col4 + j * 64;
      f32x4 v = *(const f32x4*)(crow + col);
      *(f32x4*)(orow0 + col) = v;  // slot0 = c (early, spreads write burst)
      const f32x4 wq = *(const f32x4*)(w_cq + col);
      const f32x4 wc = *(const f32x4*)(w_c + col);
      scp += v.x * wc.x + v.y * wc.y + v.z * wc.z + v.w * wc.w;
      v *= wq;
      bf16x4 bv = {(__bf16)v.x, (__bf16)v.y, (__bf16)v.z, (__bf16)v.w};
      *(bf16x4*)(lAP + (col >> 5) * kChunk + srow * 72 + (col & 31) * 2) = bv;
    }
    scp += __shfl_xor(scp, 1, 64);
    scp += __shfl_xor(scp, 2, 64);
    scp += __shfl_xor(scp, 4, 64);
    scp += __shfl_xor(scp, 8, 64);
    if ((tid & 15) == 0) scrow[srow] = scp + b_c[0];
  }
  __syncthreads();

  // ---------------- Phase 1: S = A @ qf (LDS A, 2-deep prefetch) ---------
  f32x4 acc[4][2] = {};
#pragma unroll
  for (int kk = 0; kk < 16; ++kk) {
    if (kk < 14) {
      b2[0] = *(const bf16x8*)(qg0 + ((size_t)(kk + 2) << 9));
      b2[1] = *(const bf16x8*)(qg1 + ((size_t)(kk + 2) << 9));
    }
    bf16x8 af[4];
#pragma unroll
    for (int m = 0; m < 4; ++m)
      af[m] = *(const bf16x8*)(lAP + kk * kChunk + (m * 16 + lr) * 72 + lg * 16);
#pragma unroll
    for (int m = 0; m < 4; ++m)
#pragma unroll
      for (int n = 0; n < 2; ++n)
        acc[m][n] = __builtin_amdgcn_mfma_f32_16x16x32_bf16(af[m], b0[n],
                                                            acc[m][n], 0, 0, 0);
#pragma unroll
    for (int n = 0; n < 2; ++n) {
      b0[n] = b1[n];
      b1[n] = b2[n];
    }
  }

  // biases
  const float bq = b_cq[0];
  float sqv[2];
#pragma unroll
  for (int n = 0; n < 2; ++n) sqv[n] = sq[b * kI + w * 32 + n * 16 + lr];
  float scr[4][4];
#pragma unroll
  for (int m = 0; m < 4; ++m)
#pragma unroll
    for (int r = 0; r < 4; ++r) scr[m][r] = scrow[m * 16 + lg * 4 + r] + bq;
#pragma unroll
  for (int m = 0; m < 4; ++m)
#pragma unroll
    for (int n = 0; n < 2; ++n)
#pragma unroll
      for (int r = 0; r < 4; ++r) acc[m][n][r] += scr[m][r] + sqv[n];

  // ---------------- exact softmax over i (512) ---------------------------
  float mx[4][4];
#pragma unroll
  for (int m = 0; m < 4; ++m)
#pragma unroll
    for (int r = 0; r < 4; ++r) {
      float v = fmaxf(acc[m][0][r], acc[m][1][r]);
#pragma unroll
      for (int off = 1; off <= 8; off <<= 1) v = fmaxf(v, __shfl_xor(v, off, 64));
      mx[m][r] = v;
    }
  if (lr == 0) {
#pragma unroll
    for (int m = 0; m < 4; ++m)
#pragma unroll
      for (int r = 0; r < 4; ++r)
        redm[w * kRows + m * 16 + lg * 4 + r] = mx[m][r];
  }
  __syncthreads();
  if (tid < kRows) {  // two-stage cross-wave max reduce
    float v = redm[tid];
#pragma unroll
    for (int w2 = 1; w2 < 16; ++w2) v = fmaxf(v, redm[w2 * kRows + tid]);
    rfin[tid] = v;
  }
  __syncthreads();
#pragma unroll
  for (int m = 0; m < 4; ++m)
#pragma unroll
    for (int r = 0; r < 4; ++r) mx[m][r] = rfin[m * 16 + lg * 4 + r];

  float sm[4][4] = {};
#pragma unroll
  for (int m = 0; m < 4; ++m)
#pragma unroll
    for (int n = 0; n < 2; ++n)
#pragma unroll
      for (int r = 0; r < 4; ++r) {
        const float p = __expf(acc[m][n][r] - mx[m][r]);
        acc[m][n][r] = p;
        sm[m][r] += p;
      }
#pragma unroll
  for (int m = 0; m < 4; ++m)
#pragma unroll
    for (int r = 0; r < 4; ++r)
#pragma unroll
      for (int off = 1; off <= 8; off <<= 1)
        sm[m][r] += __shfl_xor(sm[m][r], off, 64);
  if (lr == 0) {
#pragma unroll
    for (int m = 0; m < 4; ++m)
#pragma unroll
      for (int r = 0; r < 4; ++r)
        redm[w * kRows + m * 16 + lg * 4 + r] = sm[m][r];
  }
  __syncthreads();
  if (tid < kRows) {  // two-stage cross-wave sum reduce
    float v = redm[tid];
#pragma unroll
    for (int w2 = 1; w2 < 16; ++w2) v += redm[w2 * kRows + tid];
    sfin[tid] = v;
  }
  __syncthreads();
  float inv[4][4];
#pragma unroll
  for (int m = 0; m < 4; ++m)
#pragma unroll
    for (int r = 0; r < 4; ++r) inv[m][r] = 1.f / sfin[m * 16 + lg * 4 + r];

  // -------- prefetch phase-2 first B frags (overlap with P publish) ------
  const __bf16* vg0 = vf + (((size_t)(b * 32 + 2 * w + 0)) * 16 << 9) + lane * 8;
  const __bf16* vg1 = vf + (((size_t)(b * 32 + 2 * w + 1)) * 16 << 9) + lane * 8;
  bf16x8 v0_[2], v1_[2], v2_[2];
  v0_[0] = *(const bf16x8*)(vg0);
  v0_[1] = *(const bf16x8*)(vg1);
  v1_[0] = *(const bf16x8*)(vg0 + (1 << 9));
  v1_[1] = *(const bf16x8*)(vg1 + (1 << 9));

  // ---------------- P (bf16) -> lAP (aliases A): chunk w, kc = n*16+lr ---
#pragma unroll
  for (int m = 0; m < 4; ++m)
#pragma unroll
    for (int r = 0; r < 4; ++r) {
      const int trow = m * 16 + lg * 4 + r;
#pragma unroll
      for (int n = 0; n < 2; ++n) {
        *(__bf16*)(lAP + w * kChunk + trow * 72 + (n * 16 + lr) * 2) =
            (__bf16)(acc[m][n][r] * inv[m][r]);
      }
    }
  __syncthreads();

  // ---------------- Phase 2: O = P @ vf (LDS A, 2-deep prefetch) ---------
  f32x4 o[4][2] = {};
#pragma unroll
  for (int kki = 0; kki < 16; ++kki) {
    if (kki < 14) {
      v2_[0] = *(const bf16x8*)(vg0 + ((size_t)(kki + 2) << 9));
      v2_[1] = *(const bf16x8*)(vg1 + ((size_t)(kki + 2) << 9));
    }
    bf16x8 af[4];
#pragma unroll
    for (int m = 0; m < 4; ++m)
      af[m] = *(const bf16x8*)(lAP + kki * kChunk + (m * 16 + lr) * 72 + lg * 16);
#pragma unroll
    for (int m = 0; m < 4; ++m)
#pragma unroll
      for (int n = 0; n < 2; ++n)
        o[m][n] = __builtin_amdgcn_mfma_f32_16x16x32_bf16(af[m], v0_[n],
                                                          o[m][n], 0, 0, 0);
#pragma unroll
    for (int n = 0; n < 2; ++n) {
      v0_[n] = v1_[n];
      v1_[n] = v2_[n];
    }
  }

  // ---- epilogue: slots [c2q | c*c2q]; fused q2c partials ----------------
  float m_tile;
  {
    float v = mx[0][0];
#pragma unroll
    for (int m = 0; m < 4; ++m)
#pragma unroll
      for (int r = 0; r < 4; ++r) v = fmaxf(v, mx[m][r]);
    v = fmaxf(v, __shfl_xor(v, 16, 64));
    v = fmaxf(v, __shfl_xor(v, 32, 64));
    m_tile = v;
  }
  float u[2] = {};
  float zz = 0.f;
#pragma unroll
  for (int m = 0; m < 4; ++m)
#pragma unroll
    for (int r = 0; r < 4; ++r) {
      const int t = t0 + m * 16 + lg * 4 + r;
      const size_t rb = (size_t)(b * kT + t);
      const float* crow = c + rb * kD;
      float* orow = out + rb * kW;
      const float ev = __expf(mx[m][r] - m_tile);
      zz += ev;
#pragma unroll
      for (int n = 0; n < 2; ++n) {
        const int d = w * 32 + n * 16 + lr;
        const float cvv = crow[d];
        const float pv = o[m][n][r];
        orow[kD + d] = pv;
        orow[2 * kD + d] = cvv * pv;
        u[n] += ev * cvv;
      }
    }
#pragma unroll
  for (int n = 0; n < 2; ++n) {
    u[n] += __shfl_xor(u[n], 16, 64);
    u[n] += __shfl_xor(u[n], 32, 64);
  }
  if (lg == 0) {
    float* ub = u_tile + ((size_t)(b * kTiles + tile)) * kD;
#pragma unroll
    for (int n = 0; n < 2; ++n) ub[w * 32 + n * 16 + lr] = u[n];
  }
  if (w == 0) {
    zz += __shfl_xor(zz, 16, 64);
    zz += __shfl_xor(zz, 32, 64);
    if (lane == 0) {
      mz[b * 64 + tile] = m_tile;
      mz[b * 64 + 32 + tile] = zz;
    }
  }
}

// q2c[b,d] = (sum_k e^{m_k-M} u_k[d]) / (sum_k e^{m_k-M} z_k)
__global__ __launch_bounds__(512) void merge_q2c_kernel(
    const float* __restrict__ mz, const float* __restrict__ u_tile,
    float* __restrict__ q2c) {
  const int b = blockIdx.x;
  const int d = threadIdx.x;
  __shared__ float sM[32], sZ[32];
  if (d < 32) {
    sM[d] = mz[b * 64 + d];
    sZ[d] = mz[b * 64 + 32 + d];
  }
  __syncthreads();
  float M = sM[0];
#pragma unroll
  for (int k = 1; k < 32; ++k) M = fmaxf(M, sM[k]);
  float Z = 0.f;
  float s = 0.f;
#pragma unroll
  for (int k = 0; k < 32; ++k) {
    const float wk = __expf(sM[k] - M);
    Z += wk * sZ[k];
    s += wk * u_tile[((size_t)(b * kTiles + k)) * kD + d];
  }
  q2c[b * kD + d] = s / Z;
}

__global__ __launch_bounds__(128) void slot3_kernel(
    const float* __restrict__ c, const float* __restrict__ q2c,
    float* __restrict__ out) {
  const int row = blockIdx.x;  // b*kT + t
  const int b = row >> 11;
  const int x4 = threadIdx.x * 4;
  f32x4 cv = *(const f32x4*)(c + (size_t)row * kD + x4);
  f32x4 qc = *(const f32x4*)(q2c + b * kD + x4);
  *(f32x4*)(out + (size_t)row * kW + 3 * kD + x4) = cv * qc;
}

extern "C" void kernel_launch(void* const* d_in, const int* in_sizes, int n_in,
                              void* d_out, int out_size, void* d_ws, size_t ws_size,
                              hipStream_t stream) {
  const float* c    = (const float*)d_in[0];
  const float* q    = (const float*)d_in[1];
  const float* w_c  = (const float*)d_in[2];
  const float* b_c  = (const float*)d_in[3];
  const float* w_q  = (const float*)d_in[4];
  const float* b_q  = (const float*)d_in[5];
  const float* w_cq = (const float*)d_in[6];
  const float* b_cq = (const float*)d_in[7];
  float* out = (float*)d_out;
  float* ws = (float*)d_ws;

  // ws layout (floats): sq 4096 | q2c 4096 | mz 512 | u_tile 131072 ;
  // then bf16: qf 2M | vf 2M   (~9 MB total)
  float* sq     = ws;
  float* q2c    = sq + kB * kI;
  float* mz     = q2c + kB * kD;
  float* u_tile = mz + kB * 64;
  __bf16* qf = (__bf16*)(u_tile + (size_t)kB * kTiles * kD);
  __bf16* vf = qf + (size_t)kB * kI * kD;

  dim3 gpq(kI / 16, kB);
  prep_qf_kernel<<<gpq, 256, 0, stream>>>(q, w_q, b_q, sq, qf);
  dim3 gpv(kI / 64, kD / 64, kB);
  prep_vf_kernel<<<gpv, 256, 0, stream>>>(q, vf);

  // 1D grid: bid = tile*8 + batch (batch pinned to XCD; 256 % 8 == 0)
  fused_attn<<<kB * kTiles, 1024, 0, stream>>>(c, qf, vf, w_cq, w_c, b_c,
                                               b_cq, sq, out, mz, u_tile);

  merge_q2c_kernel<<<kB, 512, 0, stream>>>(mz, u_tile, q2c);
  slot3_kernel<<<kB * kT, 128, 0, stream>>>(c, q2c, out);
}